// Round 1
// baseline (3642.081 us; speedup 1.0000x reference)
//
#include <hip/hip_runtime.h>
#include <math.h>

#define NN 32768
#define NE 524288

__device__ __forceinline__ float sspf(float x) {
    // softplus(x) - ln2, numerically stable
    float r = fmaxf(x, 0.0f) + log1pf(expf(-fabsf(x)));
    return r - 0.69314718055994530942f;
}

// ---------------- Kernel 1: node embedding ----------------
// embed[n][0:16]  = (s @ W1_0e) / 8
// embed[n][16+f*3+d] = (sum_c v[c][d] * W1_1o[c][f]) / sqrt(32)
__global__ __launch_bounds__(256) void embed_kernel(
    const float* __restrict__ x,
    const float* __restrict__ W1s,   // (64,16)
    const float* __restrict__ W1v,   // (32,16)
    float* __restrict__ embed)
{
    __shared__ float sWs[1024];
    __shared__ float sWv[512];
    int t = threadIdx.x;
    for (int k = t; k < 1024; k += 256) sWs[k] = W1s[k];
    for (int k = t; k < 512;  k += 256) sWv[k] = W1v[k];
    __syncthreads();

    int n = blockIdx.x * 256 + t;
    const float* xr = x + (size_t)n * 160;

    float s1[16];
#pragma unroll
    for (int f = 0; f < 16; f++) s1[f] = 0.f;
#pragma unroll
    for (int cq = 0; cq < 16; cq++) {
        float4 sv = ((const float4*)xr)[cq];
        int c = cq * 4;
#pragma unroll
        for (int f = 0; f < 16; f++) {
            s1[f] += sv.x * sWs[(c+0)*16+f] + sv.y * sWs[(c+1)*16+f]
                   + sv.z * sWs[(c+2)*16+f] + sv.w * sWs[(c+3)*16+f];
        }
    }

    float v1[48];
#pragma unroll
    for (int k = 0; k < 48; k++) v1[k] = 0.f;
#pragma unroll
    for (int q = 0; q < 24; q++) {
        float4 vv = ((const float4*)(xr + 64))[q];
        float vals[4] = {vv.x, vv.y, vv.z, vv.w};
#pragma unroll
        for (int u = 0; u < 4; u++) {
            int m = q * 4 + u;
            int c = m / 3, d = m % 3;
            float val = vals[u];
#pragma unroll
            for (int f = 0; f < 16; f++)
                v1[f*3+d] += val * sWv[c*16+f];
        }
    }

    float ob[64];
#pragma unroll
    for (int f = 0; f < 16; f++) ob[f] = s1[f] * 0.125f;               // /sqrt(64)
    const float is32 = 0.17677669529663688f;                            // 1/sqrt(32)
#pragma unroll
    for (int k = 0; k < 48; k++) ob[16+k] = v1[k] * is32;

    float4* eo = (float4*)(embed + (size_t)n * 64);
#pragma unroll
    for (int q = 0; q < 16; q++) eo[q] = ((float4*)ob)[q];
}

// ---------------- Kernel 2: edge kernel ----------------
// Per edge: filter MLP (first 64 of 96 outputs only), gather embed[idx_j],
// form o-terms, atomicAdd into acc[idx_i][0:128].
// acc layout per node: [0:16]=n0a, [16:32]=n0b, [32:80]=n1a(f*3+d), [80:128]=n1b(f*3+d)
__global__ __launch_bounds__(256) void edge_kernel(
    const float* __restrict__ f_ij,     // (E,32)
    const float* __restrict__ rcut_ij,  // (E,)
    const float* __restrict__ Yr,       // (E,4)
    const int*   __restrict__ idx_i,
    const int*   __restrict__ idx_j,
    const float* __restrict__ embed,    // (N,64)
    const float* __restrict__ mW1,      // (32,16)
    const float* __restrict__ mb1,      // (16,)
    const float* __restrict__ mW2,      // (16,96) -> stage first 64 cols
    const float* __restrict__ mb2,      // (96,)
    float* __restrict__ acc)            // (N,128)
{
    __shared__ float sW1[512];
    __shared__ float sW2[1024];
    __shared__ float sb1[16];
    __shared__ float sb2[64];
    int t = threadIdx.x;
    for (int k = t; k < 512; k += 256) sW1[k] = mW1[k];
    for (int k = t; k < 1024; k += 256) {
        int f = k >> 6, c = k & 63;
        sW2[k] = mW2[f*96 + c];
    }
    if (t < 16) sb1[t] = mb1[t];
    else if (t >= 32 && t < 96) sb2[t-32] = mb2[t-32];
    __syncthreads();

    int e = blockIdx.x * 256 + t;

    // h = ssp(f @ mW1 + mb1)
    float h[16];
#pragma unroll
    for (int f = 0; f < 16; f++) h[f] = sb1[f];
    const float4* frow = (const float4*)(f_ij + (size_t)e * 32);
#pragma unroll
    for (int rq = 0; rq < 8; rq++) {
        float4 fv = frow[rq];
        int r = rq * 4;
#pragma unroll
        for (int f = 0; f < 16; f++)
            h[f] += fv.x * sW1[(r+0)*16+f] + fv.y * sW1[(r+1)*16+f]
                  + fv.z * sW1[(r+2)*16+f] + fv.w * sW1[(r+3)*16+f];
    }
#pragma unroll
    for (int f = 0; f < 16; f++) h[f] = sspf(h[f]);

    // w = (h @ mW2[:, :64] + mb2[:64]) * rcut
    float rc = rcut_ij[e];
    float w[64];
#pragma unroll
    for (int k = 0; k < 64; k++) w[k] = sb2[k];
#pragma unroll
    for (int f = 0; f < 16; f++) {
        float hf = h[f];
#pragma unroll
        for (int k = 0; k < 64; k++) w[k] += hf * sW2[f*64+k];
    }
#pragma unroll
    for (int k = 0; k < 64; k++) w[k] *= rc;

    int j = idx_j[e];
    int i = idx_i[e];
    float4 yv = ((const float4*)Yr)[e];
    float y0 = yv.x, yx = yv.y, yy = yv.z, yz = yv.w;

    float em[64];
    const float4* ej = (const float4*)(embed + (size_t)j * 64);
#pragma unroll
    for (int q = 0; q < 16; q++) ((float4*)em)[q] = ej[q];

    float* o = acc + (size_t)i * 128;
    const float is3 = 0.5773502691896258f;   // 1/sqrt(3)
#pragma unroll
    for (int f = 0; f < 16; f++) {
        float sj = em[f];
        float vx = em[16+f*3+0], vy = em[16+f*3+1], vz = em[16+f*3+2];
        atomicAdd(o + f,      sj * y0 * w[f]);                                  // n0a
        atomicAdd(o + 16 + f, (vx*yx + vy*yy + vz*yz) * is3 * w[16+f]);         // n0b
        float wa = w[32+f];
        atomicAdd(o + 32 + f*3 + 0, sj * yx * wa);                              // n1a
        atomicAdd(o + 32 + f*3 + 1, sj * yy * wa);
        atomicAdd(o + 32 + f*3 + 2, sj * yz * wa);
        float wb = w[48+f] * y0;
        atomicAdd(o + 80 + f*3 + 0, vx * wb);                                   // n1b
        atomicAdd(o + 80 + f*3 + 1, vy * wb);
        atomicAdd(o + 80 + f*3 + 2, vz * wb);
    }
}

// ---------------- Kernel 3: node output ----------------
// One wave (64 lanes) per node; 4 nodes per 256-thread block.
// s2 = ssp(n0 @ W2_0e / sqrt32); s3 = s2 @ W3_0e / 8
// v2[c][d] = sum_f n1[f][d]*W2_1o[f][c]/sqrt32 ; v3[e][d] = sum_c v2[c][d]*W3_1o[c][e]/sqrt32
__global__ __launch_bounds__(256) void out_kernel(
    const float* __restrict__ acc,      // (N,128)
    const float* __restrict__ W2s,      // (32,64)
    const float* __restrict__ W2v,      // (32,32)
    const float* __restrict__ W3s,      // (64,64)
    const float* __restrict__ W3v,      // (32,32)
    float* __restrict__ out)            // (N,160)
{
    __shared__ float lds[4][288];  // [0:128]=nbuf, [128:192]=s2, [192:288]=v2
    int t = threadIdx.x;
    int wv = t >> 6, ln = t & 63;
    int n = blockIdx.x * 4 + wv;
    float* L = lds[wv];
    const float* a = acc + (size_t)n * 128;
    L[ln] = a[ln];
    L[64+ln] = a[64+ln];
    __syncthreads();

    const float is32 = 0.17677669529663688f;

    // s2[ln]
    float s_acc = 0.f;
#pragma unroll
    for (int g = 0; g < 32; g++) s_acc += L[g] * W2s[g*64 + ln];
    float s2 = sspf(s_acc * is32);

    // v2: output index o = c*3+d; lane ln computes o=ln, and o=ln+64 if ln<32
    float v2a = 0.f, v2b = 0.f;
    int c1 = ln / 3, d1 = ln % 3;
    int o2i = ln + 64;
    int c2 = o2i / 3, d2 = o2i % 3;
#pragma unroll
    for (int f = 0; f < 32; f++) {
        v2a += L[32 + f*3 + d1] * W2v[f*32 + c1];
        if (ln < 32) v2b += L[32 + f*3 + d2] * W2v[f*32 + c2];
    }

    L[128 + ln] = s2;
    L[192 + ln] = v2a * is32;
    if (ln < 32) L[192 + 64 + ln] = v2b * is32;
    __syncthreads();

    // s3[ln]
    float s3 = 0.f;
#pragma unroll
    for (int k = 0; k < 64; k++) s3 += L[128+k] * W3s[k*64 + ln];
    out[(size_t)n*160 + ln] = s3 * 0.125f;

    // v3: o = e*3+d; lane ln computes o=ln, and o=ln+64 if ln<32
    int e1 = ln / 3;  // d1 same as above
    float a1 = 0.f;
#pragma unroll
    for (int c = 0; c < 32; c++) a1 += L[192 + c*3 + d1] * W3v[c*32 + e1];
    out[(size_t)n*160 + 64 + ln] = a1 * is32;
    if (ln < 32) {
        int e2 = o2i / 3;
        float a2 = 0.f;
#pragma unroll
        for (int c = 0; c < 32; c++) a2 += L[192 + c*3 + d2] * W3v[c*32 + e2];
        out[(size_t)n*160 + 64 + o2i] = a2 * is32;
    }
}

extern "C" void kernel_launch(void* const* d_in, const int* in_sizes, int n_in,
                              void* d_out, int out_size, void* d_ws, size_t ws_size,
                              hipStream_t stream) {
    const float* x     = (const float*)d_in[0];
    const float* f_ij  = (const float*)d_in[1];
    const float* rcut  = (const float*)d_in[2];
    const float* Yr    = (const float*)d_in[3];
    const float* W1s   = (const float*)d_in[4];
    const float* W1v   = (const float*)d_in[5];
    const float* mW1   = (const float*)d_in[6];
    const float* mb1   = (const float*)d_in[7];
    const float* mW2   = (const float*)d_in[8];
    const float* mb2   = (const float*)d_in[9];
    const float* W2s   = (const float*)d_in[10];
    const float* W2v   = (const float*)d_in[11];
    const float* W3s   = (const float*)d_in[12];
    const float* W3v   = (const float*)d_in[13];
    const int*   idx_i = (const int*)d_in[14];
    const int*   idx_j = (const int*)d_in[15];
    float* out = (float*)d_out;

    float* embed = (float*)d_ws;                       // N*64 floats
    float* acc   = embed + (size_t)NN * 64;            // N*128 floats

    hipMemsetAsync(acc, 0, (size_t)NN * 128 * sizeof(float), stream);
    embed_kernel<<<NN/256, 256, 0, stream>>>(x, W1s, W1v, embed);
    edge_kernel<<<NE/256, 256, 0, stream>>>(f_ij, rcut, Yr, idx_i, idx_j, embed,
                                            mW1, mb1, mW2, mb2, acc);
    out_kernel<<<NN/4, 256, 0, stream>>>(acc, W2s, W2v, W3s, W3v, out);
}

// Round 2
// 490.997 us; speedup vs baseline: 7.4177x; 7.4177x over previous
//
#include <hip/hip_runtime.h>
#include <math.h>

#define NN 32768
#define NE 524288

__device__ __forceinline__ float sspf(float x) {
    // softplus(x) - ln2, numerically stable
    float r = fmaxf(x, 0.0f) + log1pf(expf(-fabsf(x)));
    return r - 0.69314718055994530942f;
}

// ---------------- CSR build ----------------
__global__ __launch_bounds__(256) void hist_kernel(
    const int* __restrict__ idx_i, int* __restrict__ counts)
{
    int e = blockIdx.x * 256 + threadIdx.x;
    atomicAdd(&counts[idx_i[e]], 1);
}

// single block, 1024 threads, 32 counts each
__global__ __launch_bounds__(1024) void scan_kernel(
    const int* __restrict__ counts, int* __restrict__ start, int* __restrict__ cursor)
{
    __shared__ int tmp[1024];
    int tid = threadIdx.x;
    int base = tid * 32;
    int local[32];
    int sum = 0;
#pragma unroll
    for (int k = 0; k < 32; k++) { local[k] = sum; sum += counts[base + k]; }
    tmp[tid] = sum;
    __syncthreads();
    for (int off = 1; off < 1024; off <<= 1) {
        int v = 0;
        if (tid >= off) v = tmp[tid - off];
        __syncthreads();
        if (tid >= off) tmp[tid] += v;
        __syncthreads();
    }
    int excl = tmp[tid] - sum;
#pragma unroll
    for (int k = 0; k < 32; k++) {
        int s = excl + local[k];
        start[base + k] = s;
        cursor[base + k] = s;
    }
}

__global__ __launch_bounds__(256) void fill_kernel(
    const int* __restrict__ idx_i, int* __restrict__ cursor, int* __restrict__ eid)
{
    int e = blockIdx.x * 256 + threadIdx.x;
    int i = idx_i[e];
    int ofs = atomicAdd(&cursor[i], 1);
    eid[ofs] = e;
}

// ---------------- Kernel: filter MLP layer 1 (per edge) ----------------
// h[e][0:16] = ssp(f_ij[e] @ mW1 + mb1)
__global__ __launch_bounds__(256) void filt_kernel(
    const float* __restrict__ f_ij,   // (E,32)
    const float* __restrict__ mW1,    // (32,16)
    const float* __restrict__ mb1,    // (16,)
    float* __restrict__ hbuf)         // (E,16)
{
    __shared__ float sW1[512];
    __shared__ float sb1[16];
    int t = threadIdx.x;
    for (int k = t; k < 512; k += 256) sW1[k] = mW1[k];
    if (t < 16) sb1[t] = mb1[t];
    __syncthreads();

    int e = blockIdx.x * 256 + t;
    float h[16];
#pragma unroll
    for (int f = 0; f < 16; f++) h[f] = sb1[f];
    const float4* frow = (const float4*)(f_ij + (size_t)e * 32);
#pragma unroll
    for (int rq = 0; rq < 8; rq++) {
        float4 fv = frow[rq];
        int r = rq * 4;
#pragma unroll
        for (int f = 0; f < 16; f++)
            h[f] += fv.x * sW1[(r+0)*16+f] + fv.y * sW1[(r+1)*16+f]
                  + fv.z * sW1[(r+2)*16+f] + fv.w * sW1[(r+3)*16+f];
    }
#pragma unroll
    for (int f = 0; f < 16; f++) h[f] = sspf(h[f]);
    float4* ho = (float4*)(hbuf + (size_t)e * 16);
#pragma unroll
    for (int q = 0; q < 4; q++) ho[q] = ((float4*)h)[q];
}

// ---------------- Kernel 1: node embedding ----------------
__global__ __launch_bounds__(256) void embed_kernel(
    const float* __restrict__ x,
    const float* __restrict__ W1s,   // (64,16)
    const float* __restrict__ W1v,   // (32,16)
    float* __restrict__ embed)
{
    __shared__ float sWs[1024];
    __shared__ float sWv[512];
    int t = threadIdx.x;
    for (int k = t; k < 1024; k += 256) sWs[k] = W1s[k];
    for (int k = t; k < 512;  k += 256) sWv[k] = W1v[k];
    __syncthreads();

    int n = blockIdx.x * 256 + t;
    const float* xr = x + (size_t)n * 160;

    float s1[16];
#pragma unroll
    for (int f = 0; f < 16; f++) s1[f] = 0.f;
#pragma unroll
    for (int cq = 0; cq < 16; cq++) {
        float4 sv = ((const float4*)xr)[cq];
        int c = cq * 4;
#pragma unroll
        for (int f = 0; f < 16; f++) {
            s1[f] += sv.x * sWs[(c+0)*16+f] + sv.y * sWs[(c+1)*16+f]
                   + sv.z * sWs[(c+2)*16+f] + sv.w * sWs[(c+3)*16+f];
        }
    }

    float v1[48];
#pragma unroll
    for (int k = 0; k < 48; k++) v1[k] = 0.f;
#pragma unroll
    for (int q = 0; q < 24; q++) {
        float4 vv = ((const float4*)(xr + 64))[q];
        float vals[4] = {vv.x, vv.y, vv.z, vv.w};
#pragma unroll
        for (int u = 0; u < 4; u++) {
            int m = q * 4 + u;
            int c = m / 3, d = m % 3;
            float val = vals[u];
#pragma unroll
            for (int f = 0; f < 16; f++)
                v1[f*3+d] += val * sWv[c*16+f];
        }
    }

    float ob[64];
#pragma unroll
    for (int f = 0; f < 16; f++) ob[f] = s1[f] * 0.125f;
    const float is32 = 0.17677669529663688f;
#pragma unroll
    for (int k = 0; k < 48; k++) ob[16+k] = v1[k] * is32;

    float4* eo = (float4*)(embed + (size_t)n * 64);
#pragma unroll
    for (int q = 0; q < 16; q++) eo[q] = ((float4*)ob)[q];
}

// ---------------- Kernel 2: node-centric edge aggregation ----------------
// 4 threads per node; thread r handles f in [4r, 4r+4).
// acc layout per node: [0:16]=n0a, [16:32]=n0b, [32:80]=n1a(f*3+d), [80:128]=n1b(f*3+d)
__global__ __launch_bounds__(256) void nodeagg_kernel(
    const float* __restrict__ embed,   // (N,64)
    const int*   __restrict__ eid,     // (E,) sorted edge ids
    const int*   __restrict__ start,   // (N,)
    const int*   __restrict__ counts,  // (N,)
    const int*   __restrict__ idx_j,
    const float* __restrict__ Yr,      // (E,4)
    const float* __restrict__ rcut,    // (E,)
    const float* __restrict__ hbuf,    // (E,16)
    const float* __restrict__ mW2,     // (16,96)
    const float* __restrict__ mb2,     // (96,)
    float* __restrict__ acc)           // (N,128)
{
    __shared__ float sW2[1024];        // first 64 cols: sW2[f*64+c] = mW2[f*96+c]
    int t = threadIdx.x;
    for (int k = t; k < 1024; k += 256) {
        int f = k >> 6, c = k & 63;
        sW2[k] = mW2[f*96 + c];
    }
    __syncthreads();

    int gid = blockIdx.x * 256 + t;
    int node = gid >> 2;
    int r = gid & 3;
    int fb = r * 4;

    // bias values for my 16 w-columns
    float b0a[4], b0b[4], b1a[4], b1b[4];
#pragma unroll
    for (int u = 0; u < 4; u++) {
        b0a[u] = mb2[fb+u];
        b0b[u] = mb2[16+fb+u];
        b1a[u] = mb2[32+fb+u];
        b1b[u] = mb2[48+fb+u];
    }

    float a0a[4] = {0,0,0,0};
    float a0b[4] = {0,0,0,0};
    float a1a[12], a1b[12];
#pragma unroll
    for (int k = 0; k < 12; k++) { a1a[k] = 0.f; a1b[k] = 0.f; }

    int s0 = start[node];
    int cnt = counts[node];
    const float is3 = 0.5773502691896258f;   // 1/sqrt(3)

    for (int q = 0; q < cnt; q++) {
        int e = eid[s0 + q];
        int j = idx_j[e];
        float rc = rcut[e];
        float4 y = ((const float4*)Yr)[e];

        // load h row (16 floats)
        float h[16];
        const float4* hr = (const float4*)(hbuf + (size_t)e * 16);
#pragma unroll
        for (int qq = 0; qq < 4; qq++) ((float4*)h)[qq] = hr[qq];

        // w columns for my 4 f values, all 4 groups
        float w0a[4], w0b[4], w1a[4], w1b[4];
#pragma unroll
        for (int u = 0; u < 4; u++) { w0a[u]=b0a[u]; w0b[u]=b0b[u]; w1a[u]=b1a[u]; w1b[u]=b1b[u]; }
#pragma unroll
        for (int f = 0; f < 16; f++) {
            float hf = h[f];
            const float* wrow = sW2 + f*64;
#pragma unroll
            for (int u = 0; u < 4; u++) {
                w0a[u] += hf * wrow[fb+u];
                w0b[u] += hf * wrow[16+fb+u];
                w1a[u] += hf * wrow[32+fb+u];
                w1b[u] += hf * wrow[48+fb+u];
            }
        }
#pragma unroll
        for (int u = 0; u < 4; u++) { w0a[u]*=rc; w0b[u]*=rc; w1a[u]*=rc; w1b[u]*=rc; }

        // gather embed row pieces
        const float* em = embed + (size_t)j * 64;
        float4 sj4 = *(const float4*)(em + fb);
        float sj[4] = {sj4.x, sj4.y, sj4.z, sj4.w};
        float vj[12];
#pragma unroll
        for (int qq = 0; qq < 3; qq++)
            ((float4*)vj)[qq] = *(const float4*)(em + 16 + fb*3 + qq*4);

        // accumulate
#pragma unroll
        for (int u = 0; u < 4; u++) {
            float vx = vj[u*3+0], vy = vj[u*3+1], vz = vj[u*3+2];
            a0a[u] += sj[u] * y.x * w0a[u];
            a0b[u] += (vx*y.y + vy*y.z + vz*y.w) * is3 * w0b[u];
            float sw = sj[u] * w1a[u];
            a1a[u*3+0] += sw * y.y;
            a1a[u*3+1] += sw * y.z;
            a1a[u*3+2] += sw * y.w;
            float yw = y.x * w1b[u];
            a1b[u*3+0] += vx * yw;
            a1b[u*3+1] += vy * yw;
            a1b[u*3+2] += vz * yw;
        }
    }

    float* o = acc + (size_t)node * 128;
#pragma unroll
    for (int u = 0; u < 4; u++) {
        o[fb+u]    = a0a[u];
        o[16+fb+u] = a0b[u];
    }
#pragma unroll
    for (int k = 0; k < 12; k++) {
        o[32 + fb*3 + k] = a1a[k];
        o[80 + fb*3 + k] = a1b[k];
    }
}

// ---------------- Kernel 3: node output ----------------
__global__ __launch_bounds__(256) void out_kernel(
    const float* __restrict__ acc,      // (N,128)
    const float* __restrict__ W2s,      // (32,64)
    const float* __restrict__ W2v,      // (32,32)
    const float* __restrict__ W3s,      // (64,64)
    const float* __restrict__ W3v,      // (32,32)
    float* __restrict__ out)            // (N,160)
{
    __shared__ float lds[4][288];
    int t = threadIdx.x;
    int wv = t >> 6, ln = t & 63;
    int n = blockIdx.x * 4 + wv;
    float* L = lds[wv];
    const float* a = acc + (size_t)n * 128;
    L[ln] = a[ln];
    L[64+ln] = a[64+ln];
    __syncthreads();

    const float is32 = 0.17677669529663688f;

    float s_acc = 0.f;
#pragma unroll
    for (int g = 0; g < 32; g++) s_acc += L[g] * W2s[g*64 + ln];
    float s2 = sspf(s_acc * is32);

    float v2a = 0.f, v2b = 0.f;
    int c1 = ln / 3, d1 = ln % 3;
    int o2i = ln + 64;
    int c2 = o2i / 3, d2 = o2i % 3;
#pragma unroll
    for (int f = 0; f < 32; f++) {
        v2a += L[32 + f*3 + d1] * W2v[f*32 + c1];
        if (ln < 32) v2b += L[32 + f*3 + d2] * W2v[f*32 + c2];
    }

    L[128 + ln] = s2;
    L[192 + ln] = v2a * is32;
    if (ln < 32) L[192 + 64 + ln] = v2b * is32;
    __syncthreads();

    float s3 = 0.f;
#pragma unroll
    for (int k = 0; k < 64; k++) s3 += L[128+k] * W3s[k*64 + ln];
    out[(size_t)n*160 + ln] = s3 * 0.125f;

    int e1 = ln / 3;
    float a1 = 0.f;
#pragma unroll
    for (int c = 0; c < 32; c++) a1 += L[192 + c*3 + d1] * W3v[c*32 + e1];
    out[(size_t)n*160 + 64 + ln] = a1 * is32;
    if (ln < 32) {
        int e2 = o2i / 3;
        float a2 = 0.f;
#pragma unroll
        for (int c = 0; c < 32; c++) a2 += L[192 + c*3 + d2] * W3v[c*32 + e2];
        out[(size_t)n*160 + 64 + o2i] = a2 * is32;
    }
}

extern "C" void kernel_launch(void* const* d_in, const int* in_sizes, int n_in,
                              void* d_out, int out_size, void* d_ws, size_t ws_size,
                              hipStream_t stream) {
    const float* x     = (const float*)d_in[0];
    const float* f_ij  = (const float*)d_in[1];
    const float* rcut  = (const float*)d_in[2];
    const float* Yr    = (const float*)d_in[3];
    const float* W1s   = (const float*)d_in[4];
    const float* W1v   = (const float*)d_in[5];
    const float* mW1   = (const float*)d_in[6];
    const float* mb1   = (const float*)d_in[7];
    const float* mW2   = (const float*)d_in[8];
    const float* mb2   = (const float*)d_in[9];
    const float* W2s   = (const float*)d_in[10];
    const float* W2v   = (const float*)d_in[11];
    const float* W3s   = (const float*)d_in[12];
    const float* W3v   = (const float*)d_in[13];
    const int*   idx_i = (const int*)d_in[14];
    const int*   idx_j = (const int*)d_in[15];
    float* out = (float*)d_out;

    // workspace layout (floats)
    float* fws   = (float*)d_ws;
    float* embed = fws;                                  // N*64   = 2,097,152
    float* acc   = embed + (size_t)NN * 64;              // N*128  = 4,194,304
    float* hbuf  = acc   + (size_t)NN * 128;             // E*16   = 8,388,608
    int* ibase   = (int*)(hbuf + (size_t)NE * 16);
    int* counts  = ibase;                                // N
    int* start   = counts + NN;                          // N
    int* cursor  = start + NN;                           // N
    int* eid     = cursor + NN;                          // E

    hipMemsetAsync(counts, 0, (size_t)NN * sizeof(int), stream);
    hist_kernel<<<NE/256, 256, 0, stream>>>(idx_i, counts);
    scan_kernel<<<1, 1024, 0, stream>>>(counts, start, cursor);
    fill_kernel<<<NE/256, 256, 0, stream>>>(idx_i, cursor, eid);
    filt_kernel<<<NE/256, 256, 0, stream>>>(f_ij, mW1, mb1, hbuf);
    embed_kernel<<<NN/256, 256, 0, stream>>>(x, W1s, W1v, embed);
    nodeagg_kernel<<<(NN*4)/256, 256, 0, stream>>>(embed, eid, start, counts, idx_j,
                                                   Yr, rcut, hbuf, mW2, mb2, acc);
    out_kernel<<<NN/4, 256, 0, stream>>>(acc, W2s, W2v, W3s, W3v, out);
}